// Round 3
// baseline (2010.799 us; speedup 1.0000x reference)
//
#include <hip/hip_runtime.h>

// out[b,i,j,:,:] = exp6(M), M[k,l] = sum_d (x[b,j,d]-x[b,i,d]) * A[b,j,d,k,l]
// (K=8 -> 64 packed columns). Block = (b, j, ipass): 128 i's, 4 waves.
//
// R2 post-mortem: nontemporal stores were a disaster (WRITE 0.79->3.35 GB:
// nt defeats TCC write-combining -> per-16B-lane HBM transactions, and the
// write stream churns L3, killing sibling A-panel reuse -> FETCH 1.3->3.2 GB).
// This version: plain dwordx4 stores. Kept from R1:
//  - Tjrow phase deleted (fold (x_j - x_i) into MFMA A-operand).
//  - XCD-bijective swizzle (ipass siblings of each (b,j) on one XCD's L2).
//  - Two-half Taylor epilogue: LDS 25.6 KB -> 6 blocks/CU (occ ~68%).

typedef short short8 __attribute__((ext_vector_type(8)));
typedef float f32x4 __attribute__((ext_vector_type(4)));

constexpr int S = 512, D = 512, MM = 64;
constexpr int TILE_I = 128;
constexpr int TS_STRIDE = 65;   // Taylor phase (conflict-free b32 reads)
constexpr int RES_STRIDE = 68;  // write-out phase (16B-aligned rows)

// pack two f32 -> two bf16 (round-half-up) in one v_perm
__device__ inline unsigned pack2(float lo, float hi) {
  unsigned a = __float_as_uint(lo) + 0x8000u;
  unsigned b = __float_as_uint(hi) + 0x8000u;
  return __builtin_amdgcn_perm(b, a, 0x07060302);  // [a.b2,a.b3,b.b2,b.b3]
}

__global__ __launch_bounds__(256, 6)
void pt_kernel(const float* __restrict__ x, const float* __restrict__ A,
               float* __restrict__ out) {
  // XCD-grouped swizzle: gridDim.x % 8 == 0 (B*2048). XCD x gets the
  // contiguous work range [x*q, (x+1)*q), so ipass siblings share its L2.
  const int bid = blockIdx.x;
  const int q = gridDim.x >> 3;
  const int work = (bid & 7) * q + (bid >> 3);
  const int b = work >> 11;
  const int j = (work >> 2) & (S - 1);
  const int i0 = (work & 3) * TILE_I;
  const int t = threadIdx.x;
  const int w = t >> 6;
  const int L = t & 63;
  const int quad = L >> 4;
  const int l15 = L & 15;

  __shared__ short8 Bf[8 * 64];               // 8 KB  (kk*4+mt)*64+L, lane-linear
  __shared__ float TsRes[64 * RES_STRIDE];    // 17.4 KB union: Ts then Res (per half)

  const float* xb = x + (size_t)b * S * D;
  const float* Ab = A + (size_t)(b * S + j) * (size_t)(D * MM);
  const float* xjr = xb + (size_t)j * D;      // x[b,j,:] row (L1/L2-hot, 2 KB)

  f32x4 acc[2][4];
#pragma unroll
  for (int it = 0; it < 2; ++it)
#pragma unroll
    for (int mt = 0; mt < 4; ++mt) acc[it][mt] = (f32x4){0.f, 0.f, 0.f, 0.f};

  const int mcol = w * 16 + l15;
  const float* xrow0 = xb + (size_t)(i0 + w * 32 + l15) * D;  // it=0 row
  const float* xrow1 = xrow0 + (size_t)16 * D;                // it=1 row

  for (int d0 = 0; d0 < D; d0 += 64) {
    __syncthreads();  // previous chunk's Bf reads complete
    // ---- stage B fragments: wave w owns m-tile w, kk = 0,1 ----
#pragma unroll
    for (int kk = 0; kk < 2; ++kk) {
      const float* ap = Ab + (size_t)(d0 + kk * 32 + quad * 8) * MM + mcol;
      const float e0 = ap[0 * MM], e1 = ap[1 * MM], e2 = ap[2 * MM], e3 = ap[3 * MM];
      const float e4 = ap[4 * MM], e5 = ap[5 * MM], e6 = ap[6 * MM], e7 = ap[7 * MM];
      union { unsigned u[4]; short8 s; } bf;
      bf.u[0] = pack2(e0, e1); bf.u[1] = pack2(e2, e3);
      bf.u[2] = pack2(e4, e5); bf.u[3] = pack2(e6, e7);
      Bf[(kk * 4 + w) * 64 + L] = bf.s;   // ds_write_b128, lane-linear
    }
    __syncthreads();
    // ---- compute: A-operand = bf16(x_j - x_i); 2 kk x 2 i-tiles x 4 m-tiles ----
#pragma unroll
    for (int kk = 0; kk < 2; ++kk) {
      short8 bfr[4];
#pragma unroll
      for (int mt = 0; mt < 4; ++mt) bfr[mt] = Bf[(kk * 4 + mt) * 64 + L];
      const float* xjp = xjr + d0 + kk * 32 + quad * 8;   // same for both it
      const float4 j0 = *(const float4*)xjp;
      const float4 j1 = *(const float4*)(xjp + 4);
#pragma unroll
      for (int it = 0; it < 2; ++it) {
        const float* xp = (it ? xrow1 : xrow0) + d0 + kk * 32 + quad * 8;
        const float4 v0 = *(const float4*)xp;
        const float4 v1 = *(const float4*)(xp + 4);
        union { unsigned u[4]; short8 s; } af;
        af.u[0] = pack2(j0.x - v0.x, j0.y - v0.y);
        af.u[1] = pack2(j0.z - v0.z, j0.w - v0.w);
        af.u[2] = pack2(j1.x - v1.x, j1.y - v1.y);
        af.u[3] = pack2(j1.z - v1.z, j1.w - v1.w);
#pragma unroll
        for (int mt = 0; mt < 4; ++mt)
          acc[it][mt] = __builtin_amdgcn_mfma_f32_16x16x32_bf16(af.s, bfr[mt], acc[it][mt], 0, 0, 0);
      }
    }
  }

  // ---- two 64-i halves (h == it): park -> Taylor -> store, TsRes reused ----
#pragma unroll
  for (int h = 0; h < 2; ++h) {
    if (h) __syncthreads();  // previous half's Res reads complete
    // park: C/D layout col=lane&15, row=quad*4+reg; local island iL = w*16+quad*4+r
#pragma unroll
    for (int mt = 0; mt < 4; ++mt)
#pragma unroll
      for (int r = 0; r < 4; ++r)
        TsRes[(w * 16 + quad * 4 + r) * TS_STRIDE + mt * 16 + l15] = acc[h][mt][r];
    __syncthreads();

    {
      const int i_loc = t >> 2;       // 4 threads per i
      const int r0 = (t & 3) * 2;     // 2 rows each

      float Mi[8][8];
#pragma unroll
      for (int k = 0; k < 8; ++k)
#pragma unroll
        for (int l = 0; l < 8; ++l)
          Mi[k][l] = TsRes[i_loc * TS_STRIDE + k * 8 + l];  // M directly (no Tjrow)
      __syncthreads();  // all Ts reads done; TsRes becomes Res

      float Mp[2][8], res[2][8];
#pragma unroll
      for (int r = 0; r < 2; ++r)
#pragma unroll
        for (int c = 0; c < 8; ++c) {
          const float v = Mi[r0 + r][c];
          Mp[r][c] = v;
          res[r][c] = v + ((r0 + r) == c ? 1.0f : 0.0f);
        }

      const float invn[5] = {0.5f, 1.0f / 3.0f, 0.25f, 0.2f, 1.0f / 6.0f};
#pragma unroll
      for (int n = 0; n < 5; ++n) {
        float np[2][8];
#pragma unroll
        for (int r = 0; r < 2; ++r)
#pragma unroll
          for (int c = 0; c < 8; ++c) {
            float sum = 0.f;
#pragma unroll
            for (int k = 0; k < 8; ++k) sum += Mp[r][k] * Mi[k][c];
            np[r][c] = sum * invn[n];
          }
#pragma unroll
        for (int r = 0; r < 2; ++r)
#pragma unroll
          for (int c = 0; c < 8; ++c) {
            Mp[r][c] = np[r][c];
            res[r][c] += np[r][c];
          }
      }

      // stage result rows in LDS (stride 68: 16B-aligned rows)
#pragma unroll
      for (int r = 0; r < 2; ++r) {
        f32x4 lo = {res[r][0], res[r][1], res[r][2], res[r][3]};
        f32x4 hi = {res[r][4], res[r][5], res[r][6], res[r][7]};
        *(f32x4*)&TsRes[i_loc * RES_STRIDE + (r0 + r) * 8] = lo;
        *(f32x4*)&TsRes[i_loc * RES_STRIDE + (r0 + r) * 8 + 4] = hi;
      }
    }
    __syncthreads();

    // ---- store: 16 consecutive lanes cover one 256-B (i,j) island ----
    {
      const int part = t & 15;
      const int il = t >> 4;  // 0..15
#pragma unroll
      for (int step = 0; step < 4; ++step) {
        const int iL = step * 16 + il;                  // local island 0..63
        const int i = i0 + step * 32 + h * 16 + il;     // global i for this half
        const f32x4 v = *(const f32x4*)&TsRes[iL * RES_STRIDE + part * 4];
        *(f32x4*)(out + (((size_t)(b * S + i)) * S + j) * MM + part * 4) = v;
      }
    }
  }
}

extern "C" void kernel_launch(void* const* d_in, const int* in_sizes, int n_in,
                              void* d_out, int out_size, void* d_ws, size_t ws_size,
                              hipStream_t stream) {
  const float* x = (const float*)d_in[0];
  const float* A = (const float*)d_in[1];
  float* out = (float*)d_out;
  const int B = in_sizes[0] / (S * D);  // 4
  pt_kernel<<<dim3(B * S * 4), dim3(256), 0, stream>>>(x, A, out);
}

// Round 4
// 801.620 us; speedup vs baseline: 2.5084x; 2.5084x over previous
//
#include <hip/hip_runtime.h>

// out[b,i,j,:,:] = exp6(Tjrow - T_i), T[i,m] = sum_d x[b,i,d]*A[b,j,d,m], K=8 (m=64)
// Block = (b, j): ONE block owns all 512 i's as 4 sequential 128-i passes.
// The (b,j) A-panel (128 KB) is fetched from HBM once (Tjrow phase warms it);
// passes 1-3 re-read it from L2/L3. vs the 866us baseline (4 sibling blocks
// per (b,j), each fetching the panel): FETCH ~1.31GB -> ~0.55GB.
// Everything else (Tjrow fp32 phase, MFMA staging, 2-thread/i Taylor, LDS
// result staging, full-line stores, launch_bounds, numerics) == baseline.

typedef short short8 __attribute__((ext_vector_type(8)));
typedef float f32x4 __attribute__((ext_vector_type(4)));

constexpr int S = 512, D = 512, MM = 64;
constexpr int TILE_I = 128;
constexpr int TS_STRIDE = 65;   // Taylor phase (conflict-free b32 reads)
constexpr int RES_STRIDE = 68;  // write-out phase (16B-aligned rows)

// pack two f32 -> two bf16 (round-half-up) in one v_perm
__device__ inline unsigned pack2(float lo, float hi) {
  unsigned a = __float_as_uint(lo) + 0x8000u;
  unsigned b = __float_as_uint(hi) + 0x8000u;
  return __builtin_amdgcn_perm(b, a, 0x07060302);  // [a.b2,a.b3,b.b2,b.b3]
}

__global__ __launch_bounds__(256, 3)
void pt_kernel(const float* __restrict__ x, const float* __restrict__ A,
               float* __restrict__ out) {
  const int bid = blockIdx.x;
  const int b = bid >> 9;          // 512 j per b
  const int j = bid & (S - 1);
  const int t = threadIdx.x;
  const int w = t >> 6;
  const int L = t & 63;
  const int quad = L >> 4;
  const int l15 = L & 15;

  __shared__ short8 Bf[8 * 64];                   // 8 KB  (kk*4+mt)*64+L, lane-linear
  __shared__ float TsRes[TILE_I * RES_STRIDE];    // 34.8 KB union: Ts then Res
  __shared__ float Tjrow[MM];
  __shared__ float red[4][MM];

  const float* xb = x + (size_t)b * S * D;
  const float* Ab = A + (size_t)(b * S + j) * (size_t)(D * MM);

  // ---- Tjrow[m] = sum_d x[b,j,d]*A[b,j,d,m] (fp32; warms L2 with A[b,j]) ----
  {
    const int m = t & 63;
    const int part = t >> 6;
    const float* xj = xb + (size_t)j * D;
    const int dbeg = part * (D / 4);
    float acc = 0.f;
    for (int dd = 0; dd < D / 4; ++dd)
      acc += xj[dbeg + dd] * Ab[(size_t)(dbeg + dd) * MM + m];
    red[part][m] = acc;
  }
  __syncthreads();
  if (t < MM) Tjrow[t] = red[0][t] + red[1][t] + red[2][t] + red[3][t];
  // visibility: barriers inside the d-loop below precede any Tjrow read

  for (int ip = 0; ip < 4; ++ip) {
    const int i0 = ip * TILE_I;

    f32x4 acc[2][4];
#pragma unroll
    for (int it = 0; it < 2; ++it)
#pragma unroll
      for (int mt = 0; mt < 4; ++mt) acc[it][mt] = (f32x4){0.f, 0.f, 0.f, 0.f};

    const int mcol = w * 16 + l15;
    const float* xrow0 = xb + (size_t)(i0 + w * 32 + l15) * D;  // it=0 row
    const float* xrow1 = xrow0 + (size_t)16 * D;                // it=1 row

    for (int d0 = 0; d0 < D; d0 += 64) {
      __syncthreads();  // previous chunk's Bf reads (and prev pass's TsRes reads) complete
      // ---- stage B fragments: wave w owns m-tile w, kk = 0,1 ----
#pragma unroll
      for (int kk = 0; kk < 2; ++kk) {
        const float* ap = Ab + (size_t)(d0 + kk * 32 + quad * 8) * MM + mcol;
        const float e0 = ap[0 * MM], e1 = ap[1 * MM], e2 = ap[2 * MM], e3 = ap[3 * MM];
        const float e4 = ap[4 * MM], e5 = ap[5 * MM], e6 = ap[6 * MM], e7 = ap[7 * MM];
        union { unsigned u[4]; short8 s; } bf;
        bf.u[0] = pack2(e0, e1); bf.u[1] = pack2(e2, e3);
        bf.u[2] = pack2(e4, e5); bf.u[3] = pack2(e6, e7);
        Bf[(kk * 4 + w) * 64 + L] = bf.s;   // ds_write_b128, lane-linear
      }
      __syncthreads();
      // ---- compute: 2 kk sub-chunks x 2 i-tiles x 4 m-tiles ----
#pragma unroll
      for (int kk = 0; kk < 2; ++kk) {
        short8 bfr[4];
#pragma unroll
        for (int mt = 0; mt < 4; ++mt) bfr[mt] = Bf[(kk * 4 + mt) * 64 + L];
#pragma unroll
        for (int it = 0; it < 2; ++it) {
          const float* xp = (it ? xrow1 : xrow0) + d0 + kk * 32 + quad * 8;
          const float4 v0 = *(const float4*)xp;
          const float4 v1 = *(const float4*)(xp + 4);
          union { unsigned u[4]; short8 s; } af;
          af.u[0] = pack2(v0.x, v0.y); af.u[1] = pack2(v0.z, v0.w);
          af.u[2] = pack2(v1.x, v1.y); af.u[3] = pack2(v1.z, v1.w);
#pragma unroll
          for (int mt = 0; mt < 4; ++mt)
            acc[it][mt] = __builtin_amdgcn_mfma_f32_16x16x32_bf16(af.s, bfr[mt], acc[it][mt], 0, 0, 0);
        }
      }
    }

    // ---- park T in LDS: C/D layout col=lane&15, row=quad*4+reg ----
#pragma unroll
    for (int it = 0; it < 2; ++it)
#pragma unroll
      for (int mt = 0; mt < 4; ++mt)
#pragma unroll
        for (int r = 0; r < 4; ++r)
          TsRes[(w * 32 + it * 16 + quad * 4 + r) * TS_STRIDE + mt * 16 + l15] = acc[it][mt][r];
    __syncthreads();

    // ---- Taylor: 2 threads per i, 4 rows each ----
    {
      const int i_loc = t >> 1;
      const int r0 = (t & 1) * 4;

      float Mi[8][8];
#pragma unroll
      for (int k = 0; k < 8; ++k)
#pragma unroll
        for (int l = 0; l < 8; ++l)
          Mi[k][l] = Tjrow[k * 8 + l] - TsRes[i_loc * TS_STRIDE + k * 8 + l];
      __syncthreads();  // all Ts reads done; TsRes becomes Res

      float Mp[4][8], res[4][8];
#pragma unroll
      for (int r = 0; r < 4; ++r)
#pragma unroll
        for (int c = 0; c < 8; ++c) {
          const float v = Mi[r0 + r][c];
          Mp[r][c] = v;
          res[r][c] = v + ((r0 + r) == c ? 1.0f : 0.0f);
        }

      const float invn[5] = {0.5f, 1.0f / 3.0f, 0.25f, 0.2f, 1.0f / 6.0f};
#pragma unroll
      for (int n = 0; n < 5; ++n) {
        float np[4][8];
#pragma unroll
        for (int r = 0; r < 4; ++r)
#pragma unroll
          for (int c = 0; c < 8; ++c) {
            float sum = 0.f;
#pragma unroll
            for (int k = 0; k < 8; ++k) sum += Mp[r][k] * Mi[k][c];
            np[r][c] = sum * invn[n];
          }
#pragma unroll
        for (int r = 0; r < 4; ++r)
#pragma unroll
          for (int c = 0; c < 8; ++c) {
            Mp[r][c] = np[r][c];
            res[r][c] += np[r][c];
          }
      }

      // stage result rows in LDS (stride 68 keeps the read pass 2-way-free)
#pragma unroll
      for (int r = 0; r < 4; ++r) {
        f32x4 lo = {res[r][0], res[r][1], res[r][2], res[r][3]};
        f32x4 hi = {res[r][4], res[r][5], res[r][6], res[r][7]};
        *(f32x4*)&TsRes[i_loc * RES_STRIDE + (r0 + r) * 8] = lo;
        *(f32x4*)&TsRes[i_loc * RES_STRIDE + (r0 + r) * 8 + 4] = hi;
      }
    }
    __syncthreads();

    // ---- store: 16 consecutive lanes cover one 256-B (i,j) island ----
    {
      const int part = t & 15;
      const int il0 = t >> 4;  // 0..15
#pragma unroll
      for (int step = 0; step < 8; ++step) {
        const int i_loc = il0 + step * 16;
        const int i = i0 + i_loc;
        const f32x4 v = *(const f32x4*)&TsRes[i_loc * RES_STRIDE + part * 4];
        *(f32x4*)(out + (((size_t)(b * S + i)) * S + j) * MM + part * 4) = v;
      }
    }
    // next pass's first d-loop barrier orders these TsRes reads vs re-park
  }
}

extern "C" void kernel_launch(void* const* d_in, const int* in_sizes, int n_in,
                              void* d_out, int out_size, void* d_ws, size_t ws_size,
                              hipStream_t stream) {
  const float* x = (const float*)d_in[0];
  const float* A = (const float*)d_in[1];
  float* out = (float*)d_out;
  const int B = in_sizes[0] / (S * D);  // 4
  pt_kernel<<<dim3(B * S), dim3(256), 0, stream>>>(x, A, out);
}